// Round 2
// baseline (1592.126 us; speedup 1.0000x reference)
//
#include <hip/hip_runtime.h>
#include <stdint.h>

#define EPS_BN 1e-5f

// Module-owned device memory for BN statistics (avoids any d_ws overflow:
// ws usage is exactly N*64 floats).
__device__ float g_stats[128];   // [0:64) sum, [64:128) sumsq
__device__ float g_sb[128];      // [0:64) scale, [64:128) shift

// ---------------------------------------------------------------------------
// Sparse conv pass: out[n,d] = sum_k sum_c in[nbr[n,k],c] * W[k,c,d]
// wave = 64 lanes = 64 output channels d. Each wave walks a contiguous chunk
// of points with a 2-deep pipeline:
//   iter n: ds_write point n+1 (regs->LDS), issue global gathers for point
//           n+2, compute point n from LDS via broadcast ds_read_b128.
// Weight columns live in VGPRs (192 regs/lane). Invalid taps (nbr==-1,
// ~93% of the +/-1 taps) are skipped via a wave-uniform scalar branch.
// ---------------------------------------------------------------------------
template<bool DO_STATS>
__global__ __launch_bounds__(256, 2)
void conv_kernel(const float* __restrict__ in, const float* __restrict__ Wg,
                 const int* __restrict__ nbr, float* __restrict__ out,
                 int n_pts, int ppw)
{
    __shared__ __align__(16) float lds[4][4][3][64];   // [wave][ring][tap][cin]
    const int lane = threadIdx.x & 63;
    const int wv   = threadIdx.x >> 6;

    // per-lane weight columns: wK[c] = W[k, c, lane]  (coalesced across lanes)
    float w0[64], w1[64], w2[64];
    #pragma unroll
    for (int c = 0; c < 64; ++c) {
        w0[c] = Wg[          c * 64 + lane];
        w1[c] = Wg[4096 +    c * 64 + lane];
        w2[c] = Wg[8192 +    c * 64 + lane];
    }

    const int gw    = blockIdx.x * 4 + wv;
    const int start = gw * ppw;
    int end = start + ppw; if (end > n_pts) end = n_pts;
    if (start >= end) return;

    float ls = 0.f, lq = 0.f;

    float rx0, rx1, rx2;   // staged gather rows (1 float/lane) in flight
    int   rmask;

    auto issue = [&](int p) {
        int pc = (p < end) ? p : start;          // clamp (dummy, never computed)
        int j0 = nbr[pc * 3 + 0];
        int j1 = nbr[pc * 3 + 1];
        int j2 = nbr[pc * 3 + 2];
        int m = ((j0 >= 0) ? 1 : 0) | ((j1 >= 0) ? 2 : 0) | ((j2 >= 0) ? 4 : 0);
        rmask = __builtin_amdgcn_readfirstlane(m);
        long r0 = (j0 >= 0) ? j0 : pc;
        long r1 = (j1 >= 0) ? j1 : pc;
        long r2 = (j2 >= 0) ? j2 : pc;
        rx0 = in[(r0 << 6) + lane];
        rx1 = in[(r1 << 6) + lane];
        rx2 = in[(r2 << 6) + lane];
    };
    auto stage = [&](int p) {
        int s = p & 3;
        lds[wv][s][0][lane] = rx0;
        lds[wv][s][1][lane] = rx1;
        lds[wv][s][2][lane] = rx2;
    };

    int m_cur, m_nxt;
    issue(start);        m_cur = rmask;
    stage(start);
    issue(start + 1);    m_nxt = rmask;

    for (int n = start; n < end; ++n) {
        stage(n + 1);          // consumes rx (point n+1) -> LDS slot (n+1)&3
        issue(n + 2);          // rx <- rows of point n+2 (latency hidden)

        const int s = n & 3;
        const float4* x4 = (const float4*)(&lds[wv][s][0][0]);
        float a0 = 0.f, a1 = 0.f, a2 = 0.f, a3 = 0.f;

        if (m_cur & 1) {
            #pragma unroll
            for (int i = 0; i < 16; ++i) { float4 v = x4[i];
                a0 = fmaf(v.x, w0[4*i+0], a0); a1 = fmaf(v.y, w0[4*i+1], a1);
                a2 = fmaf(v.z, w0[4*i+2], a2); a3 = fmaf(v.w, w0[4*i+3], a3); }
        }
        if (m_cur & 2) {       // self tap (always valid in this dataset)
            #pragma unroll
            for (int i = 0; i < 16; ++i) { float4 v = x4[16 + i];
                a0 = fmaf(v.x, w1[4*i+0], a0); a1 = fmaf(v.y, w1[4*i+1], a1);
                a2 = fmaf(v.z, w1[4*i+2], a2); a3 = fmaf(v.w, w1[4*i+3], a3); }
        }
        if (m_cur & 4) {
            #pragma unroll
            for (int i = 0; i < 16; ++i) { float4 v = x4[32 + i];
                a0 = fmaf(v.x, w2[4*i+0], a0); a1 = fmaf(v.y, w2[4*i+1], a1);
                a2 = fmaf(v.z, w2[4*i+2], a2); a3 = fmaf(v.w, w2[4*i+3], a3); }
        }
        float val = (a0 + a1) + (a2 + a3);
        out[((long)n << 6) + lane] = val;
        if (DO_STATS) { ls += val; lq = fmaf(val, val, lq); }
        m_cur = m_nxt; m_nxt = rmask;
    }

    if (DO_STATS) {
        atomicAdd(&g_stats[lane], ls);
        atomicAdd(&g_stats[64 + lane], lq);
    }
}

__global__ void zero_stats_kernel() { g_stats[threadIdx.x] = 0.f; }

__global__ void finalize_kernel(const float* __restrict__ gamma,
                                const float* __restrict__ beta, float inv_n)
{
    int c = threadIdx.x;                  // 64 threads
    float mean = g_stats[c] * inv_n;
    float var  = g_stats[64 + c] * inv_n - mean * mean;
    float inv  = rsqrtf(var + EPS_BN);
    float sc   = gamma[c] * inv;
    g_sb[c]      = sc;
    g_sb[64 + c] = fmaf(-mean, sc, beta[c]);
}

__global__ __launch_bounds__(256)
void bn_relu_kernel(const float* __restrict__ h, float* __restrict__ out, long n4)
{
    __shared__ float4 s_s[16], s_b[16];
    if (threadIdx.x < 16) {
        s_s[threadIdx.x] = ((const float4*)g_sb)[threadIdx.x];
        s_b[threadIdx.x] = ((const float4*)g_sb)[16 + threadIdx.x];
    }
    __syncthreads();
    const float4* h4 = (const float4*)h;
    float4*       o4 = (float4*)out;
    long i      = (long)blockIdx.x * blockDim.x + threadIdx.x;
    long stride = (long)gridDim.x * blockDim.x;
    for (; i < n4; i += stride) {
        float4 v = h4[i];
        int cg = (int)(i & 15);           // 16 float4 groups per 64-ch row
        float4 s = s_s[cg], b = s_b[cg];
        float4 r;
        r.x = fmaxf(fmaf(v.x, s.x, b.x), 0.f);
        r.y = fmaxf(fmaf(v.y, s.y, b.y), 0.f);
        r.z = fmaxf(fmaf(v.z, s.z, b.z), 0.f);
        r.w = fmaxf(fmaf(v.w, s.w, b.w), 0.f);
        o4[i] = r;
    }
}

extern "C" void kernel_launch(void* const* d_in, const int* in_sizes, int n_in,
                              void* d_out, int out_size, void* d_ws, size_t ws_size,
                              hipStream_t stream)
{
    const float* feats = (const float*)d_in[0];
    const float* W1    = (const float*)d_in[1];
    const float* W2    = (const float*)d_in[2];
    const float* W3    = (const float*)d_in[3];
    const float* gamma = (const float*)d_in[4];
    const float* beta  = (const float*)d_in[5];
    const int*   nz    = (const int*)d_in[6];
    const int*   ny    = (const int*)d_in[7];
    const int*   nx    = (const int*)d_in[8];

    const int N = in_sizes[0] / 64;

    float* h    = (float*)d_ws;      // N*64 floats: h1, then reused for h3
    float* outp = (float*)d_out;     // h2, then final output

    const int NB = 512, WPB = 4;
    const int ppw = (N + NB * WPB - 1) / (NB * WPB);

    zero_stats_kernel<<<1, 128, 0, stream>>>();
    conv_kernel<false><<<NB, 256, 0, stream>>>(feats, W1, nz, h,    N, ppw);
    conv_kernel<false><<<NB, 256, 0, stream>>>(h,     W2, ny, outp, N, ppw);
    conv_kernel<true ><<<NB, 256, 0, stream>>>(outp,  W3, nx, h,    N, ppw);
    finalize_kernel<<<1, 64, 0, stream>>>(gamma, beta, 1.0f / (float)N);
    bn_relu_kernel<<<2048, 256, 0, stream>>>(h, outp, (long)N * 16);
}